// Round 2
// baseline (1748.945 us; speedup 1.0000x reference)
//
#include <hip/hip_runtime.h>
#include <cstdint>

#define TOKENS 100352
#define CDIM 384
#define HIDDIM 1536
#define NQKV 1152
#define NHEAD 12
#define NCHUNK 4
#define CHTOK (TOKENS / NCHUNK)          // 25088 tokens per chunk
#define CHWIN 512                        // windows per chunk (8 images x 64)
#define CHIMG 8                          // images per chunk

typedef __bf16 bf16x8 __attribute__((ext_vector_type(8)));
typedef float f32x4 __attribute__((ext_vector_type(4)));
typedef unsigned short u16;
typedef u16 u16x8 __attribute__((ext_vector_type(8)));

typedef __attribute__((address_space(1))) unsigned int u32_as1;
typedef __attribute__((address_space(3))) unsigned int u32_as3;

__device__ __forceinline__ float bf2f(u16 u) {
    union { unsigned int i; float f; } v; v.i = ((unsigned int)u) << 16; return v.f;
}
__device__ __forceinline__ u16 f2bf(float f) {
    union { float f; unsigned int i; } v; v.f = f;
    unsigned int i = v.i;
    i += 0x7fffu + ((i >> 16) & 1u);
    return (u16)(i >> 16);
}
__device__ __forceinline__ float gelu_f(float x) {
    return 0.5f * x * (1.0f + erff(x * 0.70710678118654752440f));
}
__device__ __forceinline__ void gload16(const u16* g, u16* l) {
    __builtin_amdgcn_global_load_lds((const u32_as1*)g, (u32_as3*)l, 16, 0, 0);
}

// ---------------- weight f32 -> bf16 cast ----------------
__global__ void cvt_kernel(const float* __restrict__ in, u16* __restrict__ out, int n) {
    int i = blockIdx.x * blockDim.x + threadIdx.x;
    if (i < n) out[i] = f2bf(in[i]);
}

// ---------------- LayerNorm: fp32 in -> bf16 out (wave per row, C=384) ----------------
__global__ __launch_bounds__(256) void ln_kernel(const float* __restrict__ x,
                                                 const float* __restrict__ w,
                                                 const float* __restrict__ b,
                                                 u16* __restrict__ out) {
    const int wid = threadIdx.x >> 6, lane = threadIdx.x & 63;
    const long row = (long)blockIdx.x * 4 + wid;
    const float* xr = x + row * CDIM;
    float v[6];
#pragma unroll
    for (int i = 0; i < 6; i++) v[i] = xr[lane + i * 64];
    float s = 0.f;
#pragma unroll
    for (int i = 0; i < 6; i++) s += v[i];
#pragma unroll
    for (int off = 32; off >= 1; off >>= 1) s += __shfl_xor(s, off, 64);
    const float mu = s * (1.0f / CDIM);
    float q = 0.f;
#pragma unroll
    for (int i = 0; i < 6; i++) { float d = v[i] - mu; q += d * d; }
#pragma unroll
    for (int off = 32; off >= 1; off >>= 1) q += __shfl_xor(q, off, 64);
    const float rs = rsqrtf(q * (1.0f / CDIM) + 1e-5f);
    u16* orow = out + row * CDIM;
#pragma unroll
    for (int i = 0; i < 6; i++) {
        const int c = lane + i * 64;
        orow[c] = f2bf((v[i] - mu) * rs * w[c] + b[c]);
    }
}

// ---------------- bf16 MFMA GEMM: C[M,N] = A[M,K] @ Bw[N,K]^T (+epilogue) ----------------
// EPI 0: out bf16 = acc                      (QKV)
// EPI 1: out f32  = acc + bias + res         (proj + residual)
// EPI 2: out bf16 = gelu(acc + bias)         (fc1)
// EPI 3: out f32  = res + gelu(acc + bias)   (fc2 + residual, in-place safe)
template <int EPI>
__global__ __launch_bounds__(256) void gemm_kernel(const u16* __restrict__ A,
                                                   const u16* __restrict__ Bw,
                                                   const float* __restrict__ bias,
                                                   const float* __restrict__ res,
                                                   void* __restrict__ outp,
                                                   int N, int K) {
    __shared__ u16 lsA[128 * 32];
    __shared__ u16 lsB[128 * 32];
    const int ntiles = N >> 7;
    const int tm = blockIdx.x / ntiles, tn = blockIdx.x % ntiles;
    const int tid = threadIdx.x, wid = tid >> 6, lane = tid & 63;
    const int wr = wid >> 1, wc = wid & 1;

    // staging: per wave: rows [wid*16, wid*16+16), 32 k-elems; LDS = linear lane*16B
    const int rstage = wid * 16 + (lane >> 2);
    const int kc8 = (lane & 3) * 8;
    const u16* gA = A + (size_t)(tm * 128 + rstage) * K + kc8;
    const u16* gB = Bw + (size_t)(tn * 128 + rstage) * K + kc8;
    u16* ldA = lsA + wid * 512;
    u16* ldB = lsB + wid * 512;
    const size_t rowskip = (size_t)64 * K;

    f32x4 acc[4][4] = {};

    const int rA = wr * 64 + (lane & 15);
    const int rB = wc * 64 + (lane & 15);
    const int kb = (lane >> 4) * 8;

    for (int k0 = 0; k0 < K; k0 += 32) {
        gload16(gA, ldA);
        gload16(gA + rowskip, ldA + 2048);
        gload16(gB, ldB);
        gload16(gB + rowskip, ldB + 2048);
        gA += 32; gB += 32;
        __syncthreads();
        bf16x8 af[4], bfr[4];
#pragma unroll
        for (int mi = 0; mi < 4; mi++)
            af[mi] = *(const bf16x8*)(lsA + (rA + mi * 16) * 32 + kb);
#pragma unroll
        for (int ni = 0; ni < 4; ni++)
            bfr[ni] = *(const bf16x8*)(lsB + (rB + ni * 16) * 32 + kb);
#pragma unroll
        for (int mi = 0; mi < 4; mi++)
#pragma unroll
            for (int ni = 0; ni < 4; ni++)
                acc[mi][ni] = __builtin_amdgcn_mfma_f32_16x16x32_bf16(af[mi], bfr[ni], acc[mi][ni], 0, 0, 0);
        __syncthreads();
    }

    const int r0 = tm * 128 + wr * 64 + ((lane >> 4) << 2);
    const int c0 = tn * 128 + wc * 64 + (lane & 15);
#pragma unroll
    for (int ni = 0; ni < 4; ni++) {
        const int col = c0 + ni * 16;
        const float bc = (EPI == 0) ? 0.0f : bias[col];
#pragma unroll
        for (int mi = 0; mi < 4; mi++) {
#pragma unroll
            for (int r = 0; r < 4; r++) {
                const size_t row = (size_t)(r0 + mi * 16 + r);
                const size_t idx = row * (size_t)N + col;
                const float v = acc[mi][ni][r];
                if (EPI == 1)      ((float*)outp)[idx] = v + bc + res[idx];
                else if (EPI == 2) ((u16*)outp)[idx] = f2bf(gelu_f(v + bc));
                else if (EPI == 3) ((float*)outp)[idx] = res[idx] + gelu_f(v + bc);
                else               ((u16*)outp)[idx] = f2bf(v);
            }
        }
    }
}

// ---------------- windowed attention: one wave per (window, head), chunk-local ----------------
__global__ __launch_bounds__(64) void attn_kernel(const u16* __restrict__ qkv,
                                                  u16* __restrict__ out) {
    const int blk = blockIdx.x;
    const int head = blk % NHEAD;
    const int win = blk / NHEAD;               // 0..CHWIN-1 (chunk-local)
    const int b = win >> 6, wy = (win >> 3) & 7, wx = win & 7;
    const int lane = threadIdx.x;
    const int base_tok = b * 3136 + wy * 7 * 56 + wx * 7;   // chunk-local token

    __shared__ float kf[49][32];
    __shared__ float vf[49][32];

    for (int ci = lane; ci < 392; ci += 64) {
        const int which = ci >= 196;
        const int c = which ? ci - 196 : ci;
        const int row = c >> 2, sub = c & 3;
        const int t = base_tok + (row / 7) * 56 + (row % 7);
        const u16* src = qkv + (size_t)t * NQKV + (which ? 768 : 384) + head * 32 + sub * 8;
        const u16x8 u = *(const u16x8*)src;
        float* dst = (which ? vf[row] : kf[row]) + sub * 8;
#pragma unroll
        for (int j = 0; j < 8; j++) dst[j] = bf2f(u[j]);
    }
    __syncthreads();

    if (lane < 49) {
        const int t = base_tok + (lane / 7) * 56 + (lane % 7);
        const u16* qsrc = qkv + (size_t)t * NQKV + head * 32;
        float qr[32];
#pragma unroll
        for (int sub = 0; sub < 4; sub++) {
            const u16x8 u = *(const u16x8*)(qsrc + sub * 8);
#pragma unroll
            for (int j = 0; j < 8; j++) qr[sub * 8 + j] = bf2f(u[j]) * 0.17677669529663688f;
        }
        float s[49];
        float mx = -1e30f;
#pragma unroll
        for (int m = 0; m < 49; m++) {
            float a = 0.f;
#pragma unroll
            for (int d = 0; d < 32; d++) a += qr[d] * kf[m][d];
            s[m] = a; mx = fmaxf(mx, a);
        }
        float sum = 0.f;
#pragma unroll
        for (int m = 0; m < 49; m++) { const float e = expf(s[m] - mx); s[m] = e; sum += e; }
        const float inv = 1.0f / sum;
        float o[32];
#pragma unroll
        for (int d = 0; d < 32; d++) o[d] = 0.f;
#pragma unroll
        for (int m = 0; m < 49; m++) {
            const float p = s[m] * inv;
#pragma unroll
            for (int d = 0; d < 32; d++) o[d] += p * vf[m][d];
        }
        u16* dst = out + (size_t)t * CDIM + head * 32;
#pragma unroll
        for (int sub = 0; sub < 4; sub++) {
            u16x8 u;
#pragma unroll
            for (int j = 0; j < 8; j++) u[j] = f2bf(o[sub * 8 + j]);
            *(u16x8*)(dst + sub * 8) = u;
        }
    }
}

extern "C" void kernel_launch(void* const* d_in, const int* in_sizes, int n_in,
                              void* d_out, int out_size, void* d_ws, size_t ws_size,
                              hipStream_t stream) {
    const float* x     = (const float*)d_in[0];
    const float* ln1w  = (const float*)d_in[1];
    const float* ln1b  = (const float*)d_in[2];
    const float* qkvw  = (const float*)d_in[3];
    const float* projw = (const float*)d_in[4];
    const float* projb = (const float*)d_in[5];
    const float* ln2w  = (const float*)d_in[6];
    const float* ln2b  = (const float*)d_in[7];
    const float* fc1w  = (const float*)d_in[8];
    const float* fc1b  = (const float*)d_in[9];
    const float* fc2w  = (const float*)d_in[10];
    const float* fc2b  = (const float*)d_in[11];
    float* out = (float*)d_out;   // also serves as x2 (attn residual) storage

    // workspace layout (~158 MB total)
    const size_t sz_xn   = (size_t)TOKENS * CDIM * 2;      // 77.1 MB
    const size_t sz_cbuf = (size_t)CHTOK * HIDDIM * 2;     // 77.1 MB (qkv chunk / y1 chunk)
    const size_t sz_w    = ((size_t)NQKV * CDIM + (size_t)CDIM * CDIM +
                            (size_t)HIDDIM * CDIM + (size_t)CDIM * HIDDIM) * 2;
    if (sz_xn + sz_cbuf + sz_w > ws_size) return;          // diagnosable, no OOB

    char* ws = (char*)d_ws;
    u16* xn   = (u16*)ws;  ws += sz_xn;    // LN output; later aliased as attn output
    u16* cbuf = (u16*)ws;  ws += sz_cbuf;  // per-chunk qkv / y1
    u16* wq = (u16*)ws; ws += (size_t)NQKV * CDIM * 2;
    u16* wp = (u16*)ws; ws += (size_t)CDIM * CDIM * 2;
    u16* w1 = (u16*)ws; ws += (size_t)HIDDIM * CDIM * 2;
    u16* w2 = (u16*)ws; ws += (size_t)CDIM * HIDDIM * 2;

    // weights -> bf16
    cvt_kernel<<<(NQKV * CDIM + 255) / 256, 256, 0, stream>>>(qkvw, wq, NQKV * CDIM);
    cvt_kernel<<<(CDIM * CDIM + 255) / 256, 256, 0, stream>>>(projw, wp, CDIM * CDIM);
    cvt_kernel<<<(HIDDIM * CDIM + 255) / 256, 256, 0, stream>>>(fc1w, w1, HIDDIM * CDIM);
    cvt_kernel<<<(CDIM * HIDDIM + 255) / 256, 256, 0, stream>>>(fc2w, w2, CDIM * HIDDIM);

    // 1) LN1: x -> xn (bf16)
    ln_kernel<<<TOKENS / 4, 256, 0, stream>>>(x, ln1w, ln1b, xn);

    // 2+3) chunked: qkv = xn[c] @ wq^T -> cbuf; attn(cbuf) -> xn[c] (in-place alias, serialized)
    for (int c = 0; c < NCHUNK; c++) {
        u16* xnc = xn + (size_t)c * CHTOK * CDIM;
        gemm_kernel<0><<<(CHTOK / 128) * (NQKV / 128), 256, 0, stream>>>(
            xnc, wq, nullptr, nullptr, cbuf, NQKV, CDIM);
        attn_kernel<<<CHWIN * NHEAD, 64, 0, stream>>>(cbuf, xnc);
    }

    // 4) out(x2) = x + attn @ proj_w^T + proj_b   (f32)
    gemm_kernel<1><<<(TOKENS / 128) * (CDIM / 128), 256, 0, stream>>>(
        xn, wp, projb, x, out, CDIM, CDIM);

    // 5) LN2: out(x2) -> xn (bf16, reuse)
    ln_kernel<<<TOKENS / 4, 256, 0, stream>>>(out, ln2w, ln2b, xn);

    // 6+7) chunked MLP: y1 = gelu(xn[c] @ w1^T + b1) -> cbuf;
    //      out[c] = out[c] + gelu(cbuf @ w2^T + b2)  (in-place res read/write, safe)
    for (int c = 0; c < NCHUNK; c++) {
        const u16* xnc = xn + (size_t)c * CHTOK * CDIM;
        float* outc = out + (size_t)c * CHTOK * CDIM;
        gemm_kernel<2><<<(CHTOK / 128) * (HIDDIM / 128), 256, 0, stream>>>(
            xnc, w1, fc1b, nullptr, cbuf, HIDDIM, CDIM);
        gemm_kernel<3><<<(CHTOK / 128) * (CDIM / 128), 256, 0, stream>>>(
            cbuf, w2, fc2b, outc, outc, CDIM, HIDDIM);
    }
}

// Round 3
// 1362.327 us; speedup vs baseline: 1.2838x; 1.2838x over previous
//
#include <hip/hip_runtime.h>
#include <cstdint>

#define TOKENS 100352
#define CDIM 384
#define HIDDIM 1536
#define NQKV 1152
#define NHEAD 12
#define NWIN_ALL 2048

typedef __bf16 bf16x8 __attribute__((ext_vector_type(8)));
typedef float f32x4 __attribute__((ext_vector_type(4)));
typedef unsigned short u16;
typedef u16 u16x8 __attribute__((ext_vector_type(8)));

typedef __attribute__((address_space(1))) unsigned int u32_as1;
typedef __attribute__((address_space(3))) unsigned int u32_as3;

__device__ __forceinline__ float bf2f(u16 u) {
    union { unsigned int i; float f; } v; v.i = ((unsigned int)u) << 16; return v.f;
}
__device__ __forceinline__ u16 f2bf(float f) {
    union { float f; unsigned int i; } v; v.f = f;
    unsigned int i = v.i;
    i += 0x7fffu + ((i >> 16) & 1u);
    return (u16)(i >> 16);
}
__device__ __forceinline__ float gelu_f(float x) {
    return 0.5f * x * (1.0f + erff(x * 0.70710678118654752440f));
}
__device__ __forceinline__ void gload16(const u16* g, u16* l) {
    __builtin_amdgcn_global_load_lds((const u32_as1*)g, (u32_as3*)l, 16, 0, 0);
}

// ---------------- weight f32 -> bf16 cast ----------------
__global__ void cvt_kernel(const float* __restrict__ in, u16* __restrict__ out, int n) {
    int i = blockIdx.x * blockDim.x + threadIdx.x;
    if (i < n) out[i] = f2bf(in[i]);
}

// ---------------- LayerNorm: fp32 in -> bf16 out (wave per row, C=384) ----------------
__global__ __launch_bounds__(256) void ln_kernel(const float* __restrict__ x,
                                                 const float* __restrict__ w,
                                                 const float* __restrict__ b,
                                                 u16* __restrict__ out) {
    const int wid = threadIdx.x >> 6, lane = threadIdx.x & 63;
    const long row = (long)blockIdx.x * 4 + wid;
    const float* xr = x + row * CDIM;
    float v[6];
#pragma unroll
    for (int i = 0; i < 6; i++) v[i] = xr[lane + i * 64];
    float s = 0.f;
#pragma unroll
    for (int i = 0; i < 6; i++) s += v[i];
#pragma unroll
    for (int off = 32; off >= 1; off >>= 1) s += __shfl_xor(s, off, 64);
    const float mu = s * (1.0f / CDIM);
    float q = 0.f;
#pragma unroll
    for (int i = 0; i < 6; i++) { float d = v[i] - mu; q += d * d; }
#pragma unroll
    for (int off = 32; off >= 1; off >>= 1) q += __shfl_xor(q, off, 64);
    const float rs = rsqrtf(q * (1.0f / CDIM) + 1e-5f);
    u16* orow = out + row * CDIM;
#pragma unroll
    for (int i = 0; i < 6; i++) {
        const int c = lane + i * 64;
        orow[c] = f2bf((v[i] - mu) * rs * w[c] + b[c]);
    }
}

// ---------------- bf16 MFMA GEMM: C[M,N] = A[M,K] @ Bw[N,K]^T (+epilogue) ----------------
// 128x128 tile, BK=64, 4 waves. XOR-swizzled LDS (pre-swizzled global src, swizzled read).
// EPI 0: out bf16 = acc                      (QKV)
// EPI 1: out f32  = acc + bias + res         (proj + residual)
// EPI 2: out bf16 = gelu(acc + bias)         (fc1)
// EPI 3: out f32  = res + gelu(acc + bias)   (fc2 + residual, in-place safe)
template <int EPI>
__global__ __launch_bounds__(256) void gemm_kernel(const u16* __restrict__ A,
                                                   const u16* __restrict__ Bw,
                                                   const float* __restrict__ bias,
                                                   const float* __restrict__ res,
                                                   void* __restrict__ outp,
                                                   int N, int K) {
    __shared__ u16 lsA[128 * 64];
    __shared__ u16 lsB[128 * 64];
    const int ntiles = N >> 7;
    const int nwg = gridDim.x;
    const int bid = blockIdx.x;
    // XCD-aware swizzle: contiguous grid chunk per XCD (bijective when nwg%8==0)
    const int wg = ((nwg & 7) == 0) ? ((bid & 7) * (nwg >> 3) + (bid >> 3)) : bid;
    const int tm = wg / ntiles, tn = wg % ntiles;
    const int tid = threadIdx.x, wid = tid >> 6, lane = tid & 63;
    const int wr = wid >> 1, wc = wid & 1;

    // staging: wave wid stages rows [wid*32, wid*32+32) in 4 instrs of 8 rows.
    // source chunk pre-swizzled so LDS slot s holds global chunk s^(row&7).
    const int srow = wid * 32 + (lane >> 3);
    const int schunk = (lane & 7) ^ (lane >> 3);      // (lane&7) ^ (row&7)
    const u16* gA = A + (size_t)(tm * 128 + srow) * K + schunk * 8;
    const u16* gB = Bw + (size_t)(tn * 128 + srow) * K + schunk * 8;
    u16* ldA = lsA + wid * 32 * 64;
    u16* ldB = lsB + wid * 32 * 64;
    const size_t rskip = (size_t)8 * K;

    f32x4 acc[4][4] = {};

    const int rA = wr * 64 + (lane & 15);
    const int rB = wc * 64 + (lane & 15);
    const int ksub = lane >> 4;      // 0..3
    const int rx = lane & 7;         // (row & 7) for fragment rows (mi*16 preserves mod 8)

    for (int k0 = 0; k0 < K; k0 += 64) {
#pragma unroll
        for (int j = 0; j < 4; j++) {
            gload16(gA + j * rskip, ldA + j * 512);
            gload16(gB + j * rskip, ldB + j * 512);
        }
        gA += 64; gB += 64;
        __syncthreads();
#pragma unroll
        for (int kk = 0; kk < 2; kk++) {
            const int ca = (((kk << 2) + ksub) ^ rx) << 3;   // swizzled chunk * 8 elems
            bf16x8 af[4], bfr[4];
#pragma unroll
            for (int mi = 0; mi < 4; mi++)
                af[mi] = *(const bf16x8*)(lsA + (rA + mi * 16) * 64 + ca);
#pragma unroll
            for (int ni = 0; ni < 4; ni++)
                bfr[ni] = *(const bf16x8*)(lsB + (rB + ni * 16) * 64 + ca);
#pragma unroll
            for (int mi = 0; mi < 4; mi++)
#pragma unroll
                for (int ni = 0; ni < 4; ni++)
                    acc[mi][ni] = __builtin_amdgcn_mfma_f32_16x16x32_bf16(af[mi], bfr[ni], acc[mi][ni], 0, 0, 0);
        }
        __syncthreads();
    }

    const int r0 = tm * 128 + wr * 64 + ((lane >> 4) << 2);
    const int c0 = tn * 128 + wc * 64 + (lane & 15);
#pragma unroll
    for (int ni = 0; ni < 4; ni++) {
        const int col = c0 + ni * 16;
        const float bc = (EPI == 0) ? 0.0f : bias[col];
#pragma unroll
        for (int mi = 0; mi < 4; mi++) {
#pragma unroll
            for (int r = 0; r < 4; r++) {
                const size_t row = (size_t)(r0 + mi * 16 + r);
                const size_t idx = row * (size_t)N + col;
                const float v = acc[mi][ni][r];
                if (EPI == 1)      ((float*)outp)[idx] = v + bc + res[idx];
                else if (EPI == 2) ((u16*)outp)[idx] = f2bf(gelu_f(v + bc));
                else if (EPI == 3) ((float*)outp)[idx] = res[idx] + gelu_f(v + bc);
                else               ((u16*)outp)[idx] = f2bf(v);
            }
        }
    }
}

// ---------------- windowed attention: one wave per (window, head), chunk-local ----------------
__global__ __launch_bounds__(64) void attn_kernel(const u16* __restrict__ qkv,
                                                  u16* __restrict__ out) {
    const int blk = blockIdx.x;
    const int head = blk % NHEAD;
    const int win = blk / NHEAD;               // chunk-local window
    const int b = win >> 6, wy = (win >> 3) & 7, wx = win & 7;
    const int lane = threadIdx.x;
    const int base_tok = b * 3136 + wy * 7 * 56 + wx * 7;   // chunk-local token

    __shared__ float kf[49][32];
    __shared__ float vf[49][32];

    for (int ci = lane; ci < 392; ci += 64) {
        const int which = ci >= 196;
        const int c = which ? ci - 196 : ci;
        const int row = c >> 2, sub = c & 3;
        const int t = base_tok + (row / 7) * 56 + (row % 7);
        const u16* src = qkv + (size_t)t * NQKV + (which ? 768 : 384) + head * 32 + sub * 8;
        const u16x8 u = *(const u16x8*)src;
        float* dst = (which ? vf[row] : kf[row]) + sub * 8;
#pragma unroll
        for (int j = 0; j < 8; j++) dst[j] = bf2f(u[j]);
    }
    __syncthreads();

    if (lane < 49) {
        const int t = base_tok + (lane / 7) * 56 + (lane % 7);
        const u16* qsrc = qkv + (size_t)t * NQKV + head * 32;
        float qr[32];
#pragma unroll
        for (int sub = 0; sub < 4; sub++) {
            const u16x8 u = *(const u16x8*)(qsrc + sub * 8);
#pragma unroll
            for (int j = 0; j < 8; j++) qr[sub * 8 + j] = bf2f(u[j]) * 0.17677669529663688f;
        }
        float s[49];
        float mx = -1e30f;
#pragma unroll
        for (int m = 0; m < 49; m++) {
            float a = 0.f;
#pragma unroll
            for (int d = 0; d < 32; d++) a += qr[d] * kf[m][d];
            s[m] = a; mx = fmaxf(mx, a);
        }
        float sum = 0.f;
#pragma unroll
        for (int m = 0; m < 49; m++) { const float e = expf(s[m] - mx); s[m] = e; sum += e; }
        const float inv = 1.0f / sum;
        float o[32];
#pragma unroll
        for (int d = 0; d < 32; d++) o[d] = 0.f;
#pragma unroll
        for (int m = 0; m < 49; m++) {
            const float p = s[m] * inv;
#pragma unroll
            for (int d = 0; d < 32; d++) o[d] += p * vf[m][d];
        }
        u16* dst = out + (size_t)t * CDIM + head * 32;
#pragma unroll
        for (int sub = 0; sub < 4; sub++) {
            u16x8 u;
#pragma unroll
            for (int j = 0; j < 8; j++) u[j] = f2bf(o[sub * 8 + j]);
            *(u16x8*)(dst + sub * 8) = u;
        }
    }
}

extern "C" void kernel_launch(void* const* d_in, const int* in_sizes, int n_in,
                              void* d_out, int out_size, void* d_ws, size_t ws_size,
                              hipStream_t stream) {
    const float* x     = (const float*)d_in[0];
    const float* ln1w  = (const float*)d_in[1];
    const float* ln1b  = (const float*)d_in[2];
    const float* qkvw  = (const float*)d_in[3];
    const float* projw = (const float*)d_in[4];
    const float* projb = (const float*)d_in[5];
    const float* ln2w  = (const float*)d_in[6];
    const float* ln2b  = (const float*)d_in[7];
    const float* fc1w  = (const float*)d_in[8];
    const float* fc1b  = (const float*)d_in[9];
    const float* fc2w  = (const float*)d_in[10];
    const float* fc2b  = (const float*)d_in[11];
    float* out = (float*)d_out;   // also serves as x2 (attn residual) storage

    const size_t sz_xn = (size_t)TOKENS * CDIM * 2;      // 77.1 MB
    const size_t sz_w  = ((size_t)NQKV * CDIM + (size_t)CDIM * CDIM +
                          (size_t)HIDDIM * CDIM + (size_t)CDIM * HIDDIM) * 2;
    if (sz_xn + sz_w > ws_size) return;
    const size_t avail = ws_size - sz_xn - sz_w;

    // adaptive chunk counts (powers of 2; deterministic in ws_size -> graph-safe)
    int nc_a = 1;
    while (nc_a <= 32 && (size_t)(TOKENS / nc_a) * NQKV * 2 > avail) nc_a <<= 1;
    int nc_m = 1;
    while (nc_m <= 16 && (size_t)(TOKENS / nc_m) * HIDDIM * 2 > avail) nc_m <<= 1;
    if (nc_a > 32 || nc_m > 16) return;

    char* ws = (char*)d_ws;
    u16* xn   = (u16*)ws;  ws += sz_xn;    // LN output; later aliased as attn output
    u16* wq = (u16*)ws; ws += (size_t)NQKV * CDIM * 2;
    u16* wp = (u16*)ws; ws += (size_t)CDIM * CDIM * 2;
    u16* w1 = (u16*)ws; ws += (size_t)HIDDIM * CDIM * 2;
    u16* w2 = (u16*)ws; ws += (size_t)CDIM * HIDDIM * 2;
    u16* cbuf = (u16*)ws;                  // per-chunk qkv / y1 (rest of ws)

    // weights -> bf16
    cvt_kernel<<<(NQKV * CDIM + 255) / 256, 256, 0, stream>>>(qkvw, wq, NQKV * CDIM);
    cvt_kernel<<<(CDIM * CDIM + 255) / 256, 256, 0, stream>>>(projw, wp, CDIM * CDIM);
    cvt_kernel<<<(HIDDIM * CDIM + 255) / 256, 256, 0, stream>>>(fc1w, w1, HIDDIM * CDIM);
    cvt_kernel<<<(CDIM * HIDDIM + 255) / 256, 256, 0, stream>>>(fc2w, w2, CDIM * HIDDIM);

    // 1) LN1: x -> xn (bf16)
    ln_kernel<<<TOKENS / 4, 256, 0, stream>>>(x, ln1w, ln1b, xn);

    // 2+3) chunked: qkv = xn[c] @ wq^T -> cbuf; attn(cbuf) -> xn[c] (alias, serialized)
    {
        const int ctok = TOKENS / nc_a;
        for (int c = 0; c < nc_a; c++) {
            u16* xnc = xn + (size_t)c * ctok * CDIM;
            gemm_kernel<0><<<(ctok / 128) * (NQKV / 128), 256, 0, stream>>>(
                xnc, wq, nullptr, nullptr, cbuf, NQKV, CDIM);
            attn_kernel<<<(NWIN_ALL / nc_a) * NHEAD, 64, 0, stream>>>(cbuf, xnc);
        }
    }

    // 4) out(x2) = x + attn @ proj_w^T + proj_b   (f32)
    gemm_kernel<1><<<(TOKENS / 128) * (CDIM / 128), 256, 0, stream>>>(
        xn, wp, projb, x, out, CDIM, CDIM);

    // 5) LN2: out(x2) -> xn (bf16, reuse)
    ln_kernel<<<TOKENS / 4, 256, 0, stream>>>(out, ln2w, ln2b, xn);

    // 6+7) chunked MLP: y1 = gelu(xn[c] @ w1^T + b1) -> cbuf;
    //      out[c] += gelu(cbuf @ w2^T + b2)  (in-place res read/write, safe)
    {
        const int ctok = TOKENS / nc_m;
        for (int c = 0; c < nc_m; c++) {
            const u16* xnc = xn + (size_t)c * ctok * CDIM;
            float* outc = out + (size_t)c * ctok * CDIM;
            gemm_kernel<2><<<(ctok / 128) * (HIDDIM / 128), 256, 0, stream>>>(
                xnc, w1, fc1b, nullptr, cbuf, HIDDIM, CDIM);
            gemm_kernel<3><<<(ctok / 128) * (CDIM / 128), 256, 0, stream>>>(
                cbuf, w2, fc2b, outc, outc, CDIM, HIDDIM);
        }
    }
}

// Round 4
// 1255.567 us; speedup vs baseline: 1.3930x; 1.0850x over previous
//
#include <hip/hip_runtime.h>
#include <cstdint>

#define TOKENS 100352
#define CDIM 384
#define HIDDIM 1536
#define NQKV 1152
#define NHEAD 12
#define NWIN_ALL 2048

typedef __bf16 bf16x8 __attribute__((ext_vector_type(8)));
typedef float f32x4 __attribute__((ext_vector_type(4)));
typedef unsigned short u16;
typedef u16 u16x8 __attribute__((ext_vector_type(8)));

typedef __attribute__((address_space(1))) unsigned int u32_as1;
typedef __attribute__((address_space(3))) unsigned int u32_as3;

__device__ __forceinline__ float bf2f(u16 u) {
    union { unsigned int i; float f; } v; v.i = ((unsigned int)u) << 16; return v.f;
}
__device__ __forceinline__ u16 f2bf(float f) {
    union { float f; unsigned int i; } v; v.f = f;
    unsigned int i = v.i;
    i += 0x7fffu + ((i >> 16) & 1u);
    return (u16)(i >> 16);
}
// branchless tanh-form GELU (max |diff| vs exact erf-GELU < 3e-4)
__device__ __forceinline__ float gelu_f(float x) {
    const float u = x * (0.7978845608028654f + 0.035677408136300125f * x * x);
    const float a = __builtin_fabsf(u);
    const float e = __expf(2.0f * a);
    float t = 1.0f - 2.0f * __builtin_amdgcn_rcpf(e + 1.0f);
    t = __builtin_copysignf(t, u);
    return 0.5f * x * (1.0f + t);
}
__device__ __forceinline__ void gload16(const u16* g, u16* l) {
    __builtin_amdgcn_global_load_lds((const u32_as1*)g, (u32_as3*)l, 16, 0, 0);
}

// ---------------- weight f32 -> bf16 cast ----------------
__global__ void cvt_kernel(const float* __restrict__ in, u16* __restrict__ out, int n) {
    int i = blockIdx.x * blockDim.x + threadIdx.x;
    if (i < n) out[i] = f2bf(in[i]);
}

// ---------------- LayerNorm: fp32 in -> bf16 out (wave per row, C=384) ----------------
__global__ __launch_bounds__(256) void ln_kernel(const float* __restrict__ x,
                                                 const float* __restrict__ w,
                                                 const float* __restrict__ b,
                                                 u16* __restrict__ out) {
    const int wid = threadIdx.x >> 6, lane = threadIdx.x & 63;
    const long row = (long)blockIdx.x * 4 + wid;
    const float* xr = x + row * CDIM;
    float v[6];
#pragma unroll
    for (int i = 0; i < 6; i++) v[i] = xr[lane + i * 64];
    float s = 0.f;
#pragma unroll
    for (int i = 0; i < 6; i++) s += v[i];
#pragma unroll
    for (int off = 32; off >= 1; off >>= 1) s += __shfl_xor(s, off, 64);
    const float mu = s * (1.0f / CDIM);
    float q = 0.f;
#pragma unroll
    for (int i = 0; i < 6; i++) { float d = v[i] - mu; q += d * d; }
#pragma unroll
    for (int off = 32; off >= 1; off >>= 1) q += __shfl_xor(q, off, 64);
    const float rs = rsqrtf(q * (1.0f / CDIM) + 1e-5f);
    u16* orow = out + row * CDIM;
#pragma unroll
    for (int i = 0; i < 6; i++) {
        const int c = lane + i * 64;
        orow[c] = f2bf((v[i] - mu) * rs * w[c] + b[c]);
    }
}

// ---------------- bf16 MFMA GEMM: C[M,N] = A[M,K] @ Bw[N,K]^T (+epilogue) ----------------
// 128x128 tile, BK=64, 4 waves, double-buffered LDS (2-phase: stage t+1 before compute t).
// XOR-swizzled LDS (pre-swizzled global src + swizzled ds_read; gload_lds dest linear).
// EPI 0: out bf16 = acc                      (QKV)
// EPI 1: out f32  = acc + bias + res         (proj + residual)
// EPI 2: out bf16 = gelu(acc + bias)         (fc1)
// EPI 3: out f32  = res + gelu(acc + bias)   (fc2 + residual, in-place safe)
template <int EPI>
__global__ __launch_bounds__(256, 2) void gemm_kernel(const u16* __restrict__ A,
                                                      const u16* __restrict__ Bw,
                                                      const float* __restrict__ bias,
                                                      const float* __restrict__ res,
                                                      void* __restrict__ outp,
                                                      int N, int K) {
    __shared__ u16 lsA0[128 * 64];
    __shared__ u16 lsB0[128 * 64];
    __shared__ u16 lsA1[128 * 64];
    __shared__ u16 lsB1[128 * 64];
    const int ntiles = N >> 7;
    const int nwg = gridDim.x;
    const int bid = blockIdx.x;
    // XCD-aware swizzle: contiguous grid chunk per XCD (bijective when nwg%8==0)
    const int wg = ((nwg & 7) == 0) ? ((bid & 7) * (nwg >> 3) + (bid >> 3)) : bid;
    const int tm = wg / ntiles, tn = wg % ntiles;
    const int tid = threadIdx.x, wid = tid >> 6, lane = tid & 63;
    const int wr = wid >> 1, wc = wid & 1;

    // staging: wave wid stages rows [wid*32, wid*32+32) in 4 instrs of 8 rows.
    // source chunk pre-swizzled so LDS slot s holds global chunk s^(row&7).
    const int srow = wid * 32 + (lane >> 3);
    const int schunk = (lane & 7) ^ (lane >> 3);
    const u16* gA = A + (size_t)(tm * 128 + srow) * K + schunk * 8;
    const u16* gB = Bw + (size_t)(tn * 128 + srow) * K + schunk * 8;
    const size_t rskip = (size_t)8 * K;
    const int lofs = wid * 2048;   // elements

    f32x4 acc[4][4] = {};

    const int rA = wr * 64 + (lane & 15);
    const int rB = wc * 64 + (lane & 15);
    const int ksub = lane >> 4;    // 0..3
    const int rx = lane & 7;       // (row & 7) for fragment rows (mi*16 preserves mod 8)

    auto STAGE = [&](u16* la, u16* lb, int kofs) {
#pragma unroll
        for (int j = 0; j < 4; j++) {
            gload16(gA + kofs + j * rskip, la + lofs + j * 512);
            gload16(gB + kofs + j * rskip, lb + lofs + j * 512);
        }
    };
    auto COMPUTE = [&](const u16* la, const u16* lb) {
#pragma unroll
        for (int kk = 0; kk < 2; kk++) {
            const int ca = (((kk << 2) + ksub) ^ rx) << 3;   // swizzled chunk * 8 elems
            bf16x8 af[4], bfr[4];
#pragma unroll
            for (int mi = 0; mi < 4; mi++)
                af[mi] = *(const bf16x8*)(la + (rA + mi * 16) * 64 + ca);
#pragma unroll
            for (int ni = 0; ni < 4; ni++)
                bfr[ni] = *(const bf16x8*)(lb + (rB + ni * 16) * 64 + ca);
#pragma unroll
            for (int mi = 0; mi < 4; mi++)
#pragma unroll
                for (int ni = 0; ni < 4; ni++)
                    acc[mi][ni] = __builtin_amdgcn_mfma_f32_16x16x32_bf16(af[mi], bfr[ni], acc[mi][ni], 0, 0, 0);
        }
    };

    // 2-phase pipeline: stage(t+1) issued BEFORE compute(t); one __syncthreads per step
    // (its vmcnt(0) waits on loads that had the whole compute phase to land).
    STAGE(lsA0, lsB0, 0);
    __syncthreads();
    const int nt = K >> 6;                  // 6 (K=384) or 24 (K=1536): always even
    for (int t = 0; t < nt; t += 2) {
        STAGE(lsA1, lsB1, (t + 1) << 6);
        COMPUTE(lsA0, lsB0);
        __syncthreads();
        if (t + 2 < nt) STAGE(lsA0, lsB0, (t + 2) << 6);
        COMPUTE(lsA1, lsB1);
        __syncthreads();
    }

    const int r0 = tm * 128 + wr * 64 + ((lane >> 4) << 2);
    const int c0 = tn * 128 + wc * 64 + (lane & 15);
#pragma unroll
    for (int ni = 0; ni < 4; ni++) {
        const int col = c0 + ni * 16;
        const float bc = (EPI == 0) ? 0.0f : bias[col];
#pragma unroll
        for (int mi = 0; mi < 4; mi++) {
#pragma unroll
            for (int r = 0; r < 4; r++) {
                const size_t row = (size_t)(r0 + mi * 16 + r);
                const size_t idx = row * (size_t)N + col;
                const float v = acc[mi][ni][r];
                if (EPI == 1)      ((float*)outp)[idx] = v + bc + res[idx];
                else if (EPI == 2) ((u16*)outp)[idx] = f2bf(gelu_f(v + bc));
                else if (EPI == 3) ((float*)outp)[idx] = res[idx] + gelu_f(v + bc);
                else               ((u16*)outp)[idx] = f2bf(v);
            }
        }
    }
}

// ---------------- windowed attention: one wave per (window, head), chunk-local ----------------
__global__ __launch_bounds__(64) void attn_kernel(const u16* __restrict__ qkv,
                                                  u16* __restrict__ out) {
    const int blk = blockIdx.x;
    const int head = blk % NHEAD;
    const int win = blk / NHEAD;               // chunk-local window
    const int b = win >> 6, wy = (win >> 3) & 7, wx = win & 7;
    const int lane = threadIdx.x;
    const int base_tok = b * 3136 + wy * 7 * 56 + wx * 7;   // chunk-local token

    __shared__ float kf[49][32];
    __shared__ float vf[49][32];

    for (int ci = lane; ci < 392; ci += 64) {
        const int which = ci >= 196;
        const int c = which ? ci - 196 : ci;
        const int row = c >> 2, sub = c & 3;
        const int t = base_tok + (row / 7) * 56 + (row % 7);
        const u16* src = qkv + (size_t)t * NQKV + (which ? 768 : 384) + head * 32 + sub * 8;
        const u16x8 u = *(const u16x8*)src;
        float* dst = (which ? vf[row] : kf[row]) + sub * 8;
#pragma unroll
        for (int j = 0; j < 8; j++) dst[j] = bf2f(u[j]);
    }
    __syncthreads();

    if (lane < 49) {
        const int t = base_tok + (lane / 7) * 56 + (lane % 7);
        const u16* qsrc = qkv + (size_t)t * NQKV + head * 32;
        float qr[32];
#pragma unroll
        for (int sub = 0; sub < 4; sub++) {
            const u16x8 u = *(const u16x8*)(qsrc + sub * 8);
#pragma unroll
            for (int j = 0; j < 8; j++) qr[sub * 8 + j] = bf2f(u[j]) * 0.17677669529663688f;
        }
        float s[49];
        float mx = -1e30f;
#pragma unroll
        for (int m = 0; m < 49; m++) {
            float a = 0.f;
#pragma unroll
            for (int d = 0; d < 32; d++) a += qr[d] * kf[m][d];
            s[m] = a; mx = fmaxf(mx, a);
        }
        float sum = 0.f;
#pragma unroll
        for (int m = 0; m < 49; m++) { const float e = expf(s[m] - mx); s[m] = e; sum += e; }
        const float inv = 1.0f / sum;
        float o[32];
#pragma unroll
        for (int d = 0; d < 32; d++) o[d] = 0.f;
#pragma unroll
        for (int m = 0; m < 49; m++) {
            const float p = s[m] * inv;
#pragma unroll
            for (int d = 0; d < 32; d++) o[d] += p * vf[m][d];
        }
        u16* dst = out + (size_t)t * CDIM + head * 32;
#pragma unroll
        for (int sub = 0; sub < 4; sub++) {
            u16x8 u;
#pragma unroll
            for (int j = 0; j < 8; j++) u[j] = f2bf(o[sub * 8 + j]);
            *(u16x8*)(dst + sub * 8) = u;
        }
    }
}

extern "C" void kernel_launch(void* const* d_in, const int* in_sizes, int n_in,
                              void* d_out, int out_size, void* d_ws, size_t ws_size,
                              hipStream_t stream) {
    const float* x     = (const float*)d_in[0];
    const float* ln1w  = (const float*)d_in[1];
    const float* ln1b  = (const float*)d_in[2];
    const float* qkvw  = (const float*)d_in[3];
    const float* projw = (const float*)d_in[4];
    const float* projb = (const float*)d_in[5];
    const float* ln2w  = (const float*)d_in[6];
    const float* ln2b  = (const float*)d_in[7];
    const float* fc1w  = (const float*)d_in[8];
    const float* fc1b  = (const float*)d_in[9];
    const float* fc2w  = (const float*)d_in[10];
    const float* fc2b  = (const float*)d_in[11];
    float* out = (float*)d_out;   // also serves as x2 (attn residual) storage

    const size_t sz_xn = (size_t)TOKENS * CDIM * 2;      // 77.1 MB
    const size_t sz_w  = ((size_t)NQKV * CDIM + (size_t)CDIM * CDIM +
                          (size_t)HIDDIM * CDIM + (size_t)CDIM * HIDDIM) * 2;
    if (sz_xn + sz_w > ws_size) return;
    const size_t avail = ws_size - sz_xn - sz_w;

    // adaptive chunk counts (powers of 2; deterministic in ws_size -> graph-safe)
    int nc_a = 1;
    while (nc_a <= 32 && (size_t)(TOKENS / nc_a) * NQKV * 2 > avail) nc_a <<= 1;
    int nc_m = 1;
    while (nc_m <= 16 && (size_t)(TOKENS / nc_m) * HIDDIM * 2 > avail) nc_m <<= 1;
    if (nc_a > 32 || nc_m > 16) return;

    char* ws = (char*)d_ws;
    u16* xn   = (u16*)ws;  ws += sz_xn;    // LN output; later aliased as attn output
    u16* wq = (u16*)ws; ws += (size_t)NQKV * CDIM * 2;
    u16* wp = (u16*)ws; ws += (size_t)CDIM * CDIM * 2;
    u16* w1 = (u16*)ws; ws += (size_t)HIDDIM * CDIM * 2;
    u16* w2 = (u16*)ws; ws += (size_t)CDIM * HIDDIM * 2;
    u16* cbuf = (u16*)ws;                  // per-chunk qkv / y1 (rest of ws)

    // weights -> bf16
    cvt_kernel<<<(NQKV * CDIM + 255) / 256, 256, 0, stream>>>(qkvw, wq, NQKV * CDIM);
    cvt_kernel<<<(CDIM * CDIM + 255) / 256, 256, 0, stream>>>(projw, wp, CDIM * CDIM);
    cvt_kernel<<<(HIDDIM * CDIM + 255) / 256, 256, 0, stream>>>(fc1w, w1, HIDDIM * CDIM);
    cvt_kernel<<<(CDIM * HIDDIM + 255) / 256, 256, 0, stream>>>(fc2w, w2, CDIM * HIDDIM);

    // 1) LN1: x -> xn (bf16)
    ln_kernel<<<TOKENS / 4, 256, 0, stream>>>(x, ln1w, ln1b, xn);

    // 2+3) chunked: qkv = xn[c] @ wq^T -> cbuf; attn(cbuf) -> xn[c] (alias, serialized)
    {
        const int ctok = TOKENS / nc_a;
        for (int c = 0; c < nc_a; c++) {
            u16* xnc = xn + (size_t)c * ctok * CDIM;
            gemm_kernel<0><<<(ctok / 128) * (NQKV / 128), 256, 0, stream>>>(
                xnc, wq, nullptr, nullptr, cbuf, NQKV, CDIM);
            attn_kernel<<<(NWIN_ALL / nc_a) * NHEAD, 64, 0, stream>>>(cbuf, xnc);
        }
    }

    // 4) out(x2) = x + attn @ proj_w^T + proj_b   (f32)
    gemm_kernel<1><<<(TOKENS / 128) * (CDIM / 128), 256, 0, stream>>>(
        xn, wp, projb, x, out, CDIM, CDIM);

    // 5) LN2: out(x2) -> xn (bf16, reuse)
    ln_kernel<<<TOKENS / 4, 256, 0, stream>>>(out, ln2w, ln2b, xn);

    // 6+7) chunked MLP: y1 = gelu(xn[c] @ w1^T + b1) -> cbuf;
    //      out[c] += gelu(cbuf @ w2^T + b2)  (in-place res read/write, safe)
    {
        const int ctok = TOKENS / nc_m;
        for (int c = 0; c < nc_m; c++) {
            const u16* xnc = xn + (size_t)c * ctok * CDIM;
            float* outc = out + (size_t)c * ctok * CDIM;
            gemm_kernel<2><<<(ctok / 128) * (HIDDIM / 128), 256, 0, stream>>>(
                xnc, w1, fc1b, nullptr, cbuf, HIDDIM, CDIM);
            gemm_kernel<3><<<(ctok / 128) * (CDIM / 128), 256, 0, stream>>>(
                cbuf, w2, fc2b, outc, outc, CDIM, HIDDIM);
        }
    }
}

// Round 5
// 1095.915 us; speedup vs baseline: 1.5959x; 1.1457x over previous
//
#include <hip/hip_runtime.h>
#include <cstdint>

#define TOKENS 100352
#define CDIM 384
#define HIDDIM 1536
#define NQKV 1152
#define NHEAD 12
#define NWIN_ALL 2048

typedef __bf16 bf16x8 __attribute__((ext_vector_type(8)));
typedef float f32x4 __attribute__((ext_vector_type(4)));
typedef unsigned short u16;
typedef u16 u16x8 __attribute__((ext_vector_type(8)));

typedef __attribute__((address_space(1))) unsigned int u32_as1;
typedef __attribute__((address_space(3))) unsigned int u32_as3;

__device__ __forceinline__ float bf2f(u16 u) {
    union { unsigned int i; float f; } v; v.i = ((unsigned int)u) << 16; return v.f;
}
__device__ __forceinline__ u16 f2bf(float f) {
    union { float f; unsigned int i; } v; v.f = f;
    unsigned int i = v.i;
    i += 0x7fffu + ((i >> 16) & 1u);
    return (u16)(i >> 16);
}
// branchless tanh-form GELU (max |diff| vs exact erf-GELU < 3e-4)
__device__ __forceinline__ float gelu_f(float x) {
    const float u = x * (0.7978845608028654f + 0.035677408136300125f * x * x);
    const float a = __builtin_fabsf(u);
    const float e = __expf(2.0f * a);
    float t = 1.0f - 2.0f * __builtin_amdgcn_rcpf(e + 1.0f);
    t = __builtin_copysignf(t, u);
    return 0.5f * x * (1.0f + t);
}
__device__ __forceinline__ void gload16(const u16* g, u16* l) {
    __builtin_amdgcn_global_load_lds((const u32_as1*)g, (u32_as3*)l, 16, 0, 0);
}

// ---------------- weight f32 -> bf16 cast ----------------
__global__ void cvt_kernel(const float* __restrict__ in, u16* __restrict__ out, int n) {
    int i = blockIdx.x * blockDim.x + threadIdx.x;
    if (i < n) out[i] = f2bf(in[i]);
}

// ---------------- LayerNorm: fp32 in -> bf16 out (wave per row, C=384) ----------------
__global__ __launch_bounds__(256) void ln_kernel(const float* __restrict__ x,
                                                 const float* __restrict__ w,
                                                 const float* __restrict__ b,
                                                 u16* __restrict__ out) {
    const int wid = threadIdx.x >> 6, lane = threadIdx.x & 63;
    const long row = (long)blockIdx.x * 4 + wid;
    const float* xr = x + row * CDIM;
    float v[6];
#pragma unroll
    for (int i = 0; i < 6; i++) v[i] = xr[lane + i * 64];
    float s = 0.f;
#pragma unroll
    for (int i = 0; i < 6; i++) s += v[i];
#pragma unroll
    for (int off = 32; off >= 1; off >>= 1) s += __shfl_xor(s, off, 64);
    const float mu = s * (1.0f / CDIM);
    float q = 0.f;
#pragma unroll
    for (int i = 0; i < 6; i++) { float d = v[i] - mu; q += d * d; }
#pragma unroll
    for (int off = 32; off >= 1; off >>= 1) q += __shfl_xor(q, off, 64);
    const float rs = rsqrtf(q * (1.0f / CDIM) + 1e-5f);
    u16* orow = out + row * CDIM;
#pragma unroll
    for (int i = 0; i < 6; i++) {
        const int c = lane + i * 64;
        orow[c] = f2bf((v[i] - mu) * rs * w[c] + b[c]);
    }
}

// ---------------- bf16 MFMA GEMM: C[M,N] = A[M,K] @ Bw[N,K]^T (+epilogue) ----------------
// 128x128 tile, BK=64, 4 waves, double-buffered LDS (2-phase: stage t+1 before compute t).
// XOR-swizzled LDS (pre-swizzled global src + swizzled ds_read; gload_lds dest linear).
template <int EPI>
__global__ __launch_bounds__(256, 2) void gemm_kernel(const u16* __restrict__ A,
                                                      const u16* __restrict__ Bw,
                                                      const float* __restrict__ bias,
                                                      const float* __restrict__ res,
                                                      void* __restrict__ outp,
                                                      int N, int K) {
    __shared__ u16 lsA0[128 * 64];
    __shared__ u16 lsB0[128 * 64];
    __shared__ u16 lsA1[128 * 64];
    __shared__ u16 lsB1[128 * 64];
    const int ntiles = N >> 7;
    const int nwg = gridDim.x;
    const int bid = blockIdx.x;
    const int wg = ((nwg & 7) == 0) ? ((bid & 7) * (nwg >> 3) + (bid >> 3)) : bid;
    const int tm = wg / ntiles, tn = wg % ntiles;
    const int tid = threadIdx.x, wid = tid >> 6, lane = tid & 63;
    const int wr = wid >> 1, wc = wid & 1;

    const int srow = wid * 32 + (lane >> 3);
    const int schunk = (lane & 7) ^ (lane >> 3);
    const u16* gA = A + (size_t)(tm * 128 + srow) * K + schunk * 8;
    const u16* gB = Bw + (size_t)(tn * 128 + srow) * K + schunk * 8;
    const size_t rskip = (size_t)8 * K;
    const int lofs = wid * 2048;

    f32x4 acc[4][4] = {};

    const int rA = wr * 64 + (lane & 15);
    const int rB = wc * 64 + (lane & 15);
    const int ksub = lane >> 4;
    const int rx = lane & 7;

    auto STAGE = [&](u16* la, u16* lb, int kofs) {
#pragma unroll
        for (int j = 0; j < 4; j++) {
            gload16(gA + kofs + j * rskip, la + lofs + j * 512);
            gload16(gB + kofs + j * rskip, lb + lofs + j * 512);
        }
    };
    auto COMPUTE = [&](const u16* la, const u16* lb) {
#pragma unroll
        for (int kk = 0; kk < 2; kk++) {
            const int ca = (((kk << 2) + ksub) ^ rx) << 3;
            bf16x8 af[4], bfr[4];
#pragma unroll
            for (int mi = 0; mi < 4; mi++)
                af[mi] = *(const bf16x8*)(la + (rA + mi * 16) * 64 + ca);
#pragma unroll
            for (int ni = 0; ni < 4; ni++)
                bfr[ni] = *(const bf16x8*)(lb + (rB + ni * 16) * 64 + ca);
#pragma unroll
            for (int mi = 0; mi < 4; mi++)
#pragma unroll
                for (int ni = 0; ni < 4; ni++)
                    acc[mi][ni] = __builtin_amdgcn_mfma_f32_16x16x32_bf16(af[mi], bfr[ni], acc[mi][ni], 0, 0, 0);
        }
    };

    STAGE(lsA0, lsB0, 0);
    __syncthreads();
    const int nt = K >> 6;
    for (int t = 0; t < nt; t += 2) {
        STAGE(lsA1, lsB1, (t + 1) << 6);
        COMPUTE(lsA0, lsB0);
        __syncthreads();
        if (t + 2 < nt) STAGE(lsA0, lsB0, (t + 2) << 6);
        COMPUTE(lsA1, lsB1);
        __syncthreads();
    }

    const int r0 = tm * 128 + wr * 64 + ((lane >> 4) << 2);
    const int c0 = tn * 128 + wc * 64 + (lane & 15);
#pragma unroll
    for (int ni = 0; ni < 4; ni++) {
        const int col = c0 + ni * 16;
        const float bc = (EPI == 0) ? 0.0f : bias[col];
#pragma unroll
        for (int mi = 0; mi < 4; mi++) {
#pragma unroll
            for (int r = 0; r < 4; r++) {
                const size_t row = (size_t)(r0 + mi * 16 + r);
                const size_t idx = row * (size_t)N + col;
                const float v = acc[mi][ni][r];
                if (EPI == 1)      ((float*)outp)[idx] = v + bc + res[idx];
                else if (EPI == 2) ((u16*)outp)[idx] = f2bf(gelu_f(v + bc));
                else if (EPI == 3) ((float*)outp)[idx] = res[idx] + gelu_f(v + bc);
                else               ((u16*)outp)[idx] = f2bf(v);
            }
        }
    }
}

// ---------------- MFMA windowed attention: one wave per (window, head) ----------------
// Pad 49->64. Q/K/V^T fragments direct from global (predicated); P via wave-private
// swizzled LDS. Fragment mapping identical to the verified GEMM above.
__global__ __launch_bounds__(256, 4) void attn_kernel(const u16* __restrict__ qkv,
                                                      u16* __restrict__ out) {
    __shared__ u16 pbuf[4 * 64 * 64];          // 8 KB per wave
    const int wid = threadIdx.x >> 6, lane = threadIdx.x & 63;
    const int id = blockIdx.x * 4 + wid;
    const int head = id % NHEAD;
    const int win = id / NHEAD;                // chunk-local window
    const int b = win >> 6, wy = (win >> 3) & 7, wx = win & 7;
    const int base_tok = b * 3136 + wy * 392 + wx * 7;
    const int l15 = lane & 15, lg = lane >> 4;
    u16* pw = pbuf + wid * 4096;

    // ---- Q (A-side) and K (B-side) fragments, rows t*16+l15, k-dim d = lg*8..+7 ----
    bf16x8 qf[4], kf[4];
#pragma unroll
    for (int t4 = 0; t4 < 4; t4++) {
        const int r = t4 * 16 + l15;
        if (r < 49) {
            const size_t to = (size_t)(base_tok + (r / 7) * 56 + (r % 7)) * NQKV + head * 32 + lg * 8;
            qf[t4] = *(const bf16x8*)(qkv + to);
            kf[t4] = *(const bf16x8*)(qkv + to + 384);
        } else {
#pragma unroll
            for (int j = 0; j < 8; j++) { qf[t4][j] = (__bf16)0.0f; kf[t4][j] = (__bf16)0.0f; }
        }
    }

    // ---- S = Q @ K^T : 16 MFMA, K=32 (=head dim) ----
    f32x4 s[4][4] = {};
#pragma unroll
    for (int qt = 0; qt < 4; qt++)
#pragma unroll
        for (int nt = 0; nt < 4; nt++)
            s[qt][nt] = __builtin_amdgcn_mfma_f32_16x16x32_bf16(qf[qt], kf[nt], s[qt][nt], 0, 0, 0);

    // ---- mask cols >= 49 (only nt=3, l15>=1), softmax over k in C-layout ----
    const float NEG = -1e30f;
    if (l15 >= 1) {
#pragma unroll
        for (int qt = 0; qt < 4; qt++)
#pragma unroll
            for (int r = 0; r < 4; r++) s[qt][3][r] = NEG;
    }
    float rm[4][4], inv[4][4];
#pragma unroll
    for (int qt = 0; qt < 4; qt++)
#pragma unroll
        for (int r = 0; r < 4; r++) {
            float m = fmaxf(fmaxf(s[qt][0][r], s[qt][1][r]), fmaxf(s[qt][2][r], s[qt][3][r]));
#pragma unroll
            for (int off = 1; off <= 8; off <<= 1) m = fmaxf(m, __shfl_xor(m, off, 64));
            rm[qt][r] = m;
        }
    const float cexp = 0.25508682f;            // SCALE * log2(e)
#pragma unroll
    for (int qt = 0; qt < 4; qt++)
#pragma unroll
        for (int nt = 0; nt < 4; nt++)
#pragma unroll
            for (int r = 0; r < 4; r++)
                s[qt][nt][r] = exp2f((s[qt][nt][r] - rm[qt][r]) * cexp);
#pragma unroll
    for (int qt = 0; qt < 4; qt++)
#pragma unroll
        for (int r = 0; r < 4; r++) {
            float su = s[qt][0][r] + s[qt][1][r] + s[qt][2][r] + s[qt][3][r];
#pragma unroll
            for (int off = 1; off <= 8; off <<= 1) su += __shfl_xor(su, off, 64);
            inv[qt][r] = 1.0f / su;
        }

    // ---- P -> LDS (bf16, 16B-chunk XOR swizzle) ----
#pragma unroll
    for (int qt = 0; qt < 4; qt++)
#pragma unroll
        for (int nt = 0; nt < 4; nt++)
#pragma unroll
            for (int r = 0; r < 4; r++) {
                const int row = qt * 16 + lg * 4 + r;
                const int col = nt * 16 + l15;
                pw[row * 64 + (((col >> 3) ^ (row & 7)) << 3) + (col & 7)] = f2bf(s[qt][nt][r]);
            }

    // ---- V^T fragments from global (strided, predicated k<49) ----
    u16x8 vtu[2][2];
#pragma unroll
    for (int ks = 0; ks < 2; ks++)
#pragma unroll
        for (int j = 0; j < 8; j++) {
            const int k = ks * 32 + lg * 8 + j;
            u16 v0 = 0, v1 = 0;
            if (k < 49) {
                const size_t to = (size_t)(base_tok + (k / 7) * 56 + (k % 7)) * NQKV + 768 + head * 32 + l15;
                v0 = qkv[to]; v1 = qkv[to + 16];
            }
            vtu[0][ks][j] = v0; vtu[1][ks][j] = v1;
        }

    // ---- P A-frags from LDS, out = P @ V : 16 MFMA ----
    f32x4 oa[4][2] = {};
#pragma unroll
    for (int ks = 0; ks < 2; ks++) {
        bf16x8 pa[4];
#pragma unroll
        for (int qt = 0; qt < 4; qt++) {
            const int row = qt * 16 + l15;
            pa[qt] = *(const bf16x8*)(pw + row * 64 + (((ks * 4 + lg) ^ (row & 7)) << 3));
        }
#pragma unroll
        for (int qt = 0; qt < 4; qt++)
#pragma unroll
            for (int dt = 0; dt < 2; dt++)
                oa[qt][dt] = __builtin_amdgcn_mfma_f32_16x16x32_bf16(
                    pa[qt], *(const bf16x8*)&vtu[dt][ks], oa[qt][dt], 0, 0, 0);
    }

    // ---- store (rows < 49), scale by 1/rowsum ----
#pragma unroll
    for (int qt = 0; qt < 4; qt++)
#pragma unroll
        for (int r = 0; r < 4; r++) {
            const int row = qt * 16 + lg * 4 + r;
            if (row < 49) {
                const int t = base_tok + (row / 7) * 56 + (row % 7);
                u16* dst = out + (size_t)t * CDIM + head * 32 + l15;
                dst[0]  = f2bf(oa[qt][0][r] * inv[qt][r]);
                dst[16] = f2bf(oa[qt][1][r] * inv[qt][r]);
            }
        }
}

extern "C" void kernel_launch(void* const* d_in, const int* in_sizes, int n_in,
                              void* d_out, int out_size, void* d_ws, size_t ws_size,
                              hipStream_t stream) {
    const float* x     = (const float*)d_in[0];
    const float* ln1w  = (const float*)d_in[1];
    const float* ln1b  = (const float*)d_in[2];
    const float* qkvw  = (const float*)d_in[3];
    const float* projw = (const float*)d_in[4];
    const float* projb = (const float*)d_in[5];
    const float* ln2w  = (const float*)d_in[6];
    const float* ln2b  = (const float*)d_in[7];
    const float* fc1w  = (const float*)d_in[8];
    const float* fc1b  = (const float*)d_in[9];
    const float* fc2w  = (const float*)d_in[10];
    const float* fc2b  = (const float*)d_in[11];
    float* out = (float*)d_out;   // also serves as x2 (attn residual) storage

    const size_t sz_xn = (size_t)TOKENS * CDIM * 2;
    const size_t sz_w  = ((size_t)NQKV * CDIM + (size_t)CDIM * CDIM +
                          (size_t)HIDDIM * CDIM + (size_t)CDIM * HIDDIM) * 2;
    if (sz_xn + sz_w > ws_size) return;
    const size_t avail = ws_size - sz_xn - sz_w;

    int nc_a = 1;
    while (nc_a <= 32 && (size_t)(TOKENS / nc_a) * NQKV * 2 > avail) nc_a <<= 1;
    int nc_m = 1;
    while (nc_m <= 16 && (size_t)(TOKENS / nc_m) * HIDDIM * 2 > avail) nc_m <<= 1;
    if (nc_a > 32 || nc_m > 16) return;

    char* ws = (char*)d_ws;
    u16* xn   = (u16*)ws;  ws += sz_xn;
    u16* wq = (u16*)ws; ws += (size_t)NQKV * CDIM * 2;
    u16* wp = (u16*)ws; ws += (size_t)CDIM * CDIM * 2;
    u16* w1 = (u16*)ws; ws += (size_t)HIDDIM * CDIM * 2;
    u16* w2 = (u16*)ws; ws += (size_t)CDIM * HIDDIM * 2;
    u16* cbuf = (u16*)ws;

    cvt_kernel<<<(NQKV * CDIM + 255) / 256, 256, 0, stream>>>(qkvw, wq, NQKV * CDIM);
    cvt_kernel<<<(CDIM * CDIM + 255) / 256, 256, 0, stream>>>(projw, wp, CDIM * CDIM);
    cvt_kernel<<<(HIDDIM * CDIM + 255) / 256, 256, 0, stream>>>(fc1w, w1, HIDDIM * CDIM);
    cvt_kernel<<<(CDIM * HIDDIM + 255) / 256, 256, 0, stream>>>(fc2w, w2, CDIM * HIDDIM);

    ln_kernel<<<TOKENS / 4, 256, 0, stream>>>(x, ln1w, ln1b, xn);

    {
        const int ctok = TOKENS / nc_a;
        const int cwin = NWIN_ALL / nc_a;
        for (int c = 0; c < nc_a; c++) {
            u16* xnc = xn + (size_t)c * ctok * CDIM;
            gemm_kernel<0><<<(ctok / 128) * (NQKV / 128), 256, 0, stream>>>(
                xnc, wq, nullptr, nullptr, cbuf, NQKV, CDIM);
            attn_kernel<<<(cwin * NHEAD) / 4, 256, 0, stream>>>(cbuf, xnc);
        }
    }

    gemm_kernel<1><<<(TOKENS / 128) * (CDIM / 128), 256, 0, stream>>>(
        xn, wp, projb, x, out, CDIM, CDIM);

    ln_kernel<<<TOKENS / 4, 256, 0, stream>>>(out, ln2w, ln2b, xn);

    {
        const int ctok = TOKENS / nc_m;
        for (int c = 0; c < nc_m; c++) {
            const u16* xnc = xn + (size_t)c * ctok * CDIM;
            float* outc = out + (size_t)c * ctok * CDIM;
            gemm_kernel<2><<<(ctok / 128) * (HIDDIM / 128), 256, 0, stream>>>(
                xnc, w1, fc1b, nullptr, cbuf, HIDDIM, CDIM);
            gemm_kernel<3><<<(ctok / 128) * (CDIM / 128), 256, 0, stream>>>(
                cbuf, w2, fc2b, outc, outc, CDIM, HIDDIM);
        }
    }
}